// Round 1
// baseline (1587.096 us; speedup 1.0000x reference)
//
#include <hip/hip_runtime.h>
#include <hip/hip_bf16.h>

#define NNODES 100000
#define NEDGES 1600000
#define NEG_SLOPE 0.2f

__device__ __forceinline__ float wave_sum64(float v) {
#pragma unroll
    for (int off = 1; off < 64; off <<= 1) v += __shfl_xor(v, off, 64);
    return v;
}

// ---------------- CSR build ----------------

__global__ __launch_bounds__(256) void k_hist(const int* __restrict__ dst,
                                              const float* __restrict__ ea,
                                              int* __restrict__ cnt,
                                              float* __restrict__ easum) {
    int wave = threadIdx.x >> 6, lane = threadIdx.x & 63;
    float s = 0.f;
    for (int i = blockIdx.x * 256 + threadIdx.x; i < NEDGES; i += gridDim.x * 256) {
        atomicAdd(&cnt[dst[i]], 1);
        s += ea[i];
    }
    s = wave_sum64(s);
    __shared__ float ws[4];
    if (lane == 0) ws[wave] = s;
    __syncthreads();
    if (threadIdx.x == 0) atomicAdd(easum, ws[0] + ws[1] + ws[2] + ws[3]);
}

__global__ __launch_bounds__(1024) void k_scan(const int* __restrict__ cnt,
                                               int* __restrict__ rowptr) {
    __shared__ int part[1024];
    const int n = NNODES;
    int t = threadIdx.x;
    int chunk = (n + 1023) >> 10;
    int lo = t * chunk, hi = min(lo + chunk, n);
    int s = 0;
    for (int i = lo; i < hi; ++i) s += cnt[i];
    part[t] = s;
    __syncthreads();
    for (int off = 1; off < 1024; off <<= 1) {
        int v = (t >= off) ? part[t - off] : 0;
        __syncthreads();
        part[t] += v;
        __syncthreads();
    }
    int run = (t == 0) ? 0 : part[t - 1];
    for (int i = lo; i < hi; ++i) { rowptr[i] = run; run += cnt[i]; }
    if (t == 1023) rowptr[n] = part[1023];
}

__global__ __launch_bounds__(256) void k_scatter(const int* __restrict__ src,
                                                 const int* __restrict__ dst,
                                                 const float* __restrict__ ea,
                                                 const int* __restrict__ rowptr,
                                                 int* __restrict__ cursor,
                                                 int* __restrict__ ssorted,
                                                 float* __restrict__ easorted) {
    for (int i = blockIdx.x * 256 + threadIdx.x; i < NEDGES; i += gridDim.x * 256) {
        int d = dst[i];
        int pos = rowptr[d] + atomicAdd(&cursor[d], 1);
        ssorted[pos] = src[i];
        easorted[pos] = ea[i];
    }
}

// ---------------- fused dual GEMM: XL = X@Wl+bl, XR = X@Wr+br ----------------

template <int K>
__global__ __launch_bounds__(256) void k_gemm(const float* __restrict__ X,
                                              const float* __restrict__ Wl,
                                              const float* __restrict__ bl,
                                              const float* __restrict__ Wr,
                                              const float* __restrict__ br,
                                              float* __restrict__ XL,
                                              float* __restrict__ XR) {
    __shared__ float sWl[K][64];
    __shared__ float sWr[K][64];
    for (int i = threadIdx.x; i < K * 64; i += 256) {
        sWl[i >> 6][i & 63] = Wl[i];
        sWr[i >> 6][i & 63] = Wr[i];
    }
    __syncthreads();
    int wave = threadIdx.x >> 6, lane = threadIdx.x & 63;
    float blv = bl[lane], brv = br[lane];
    for (int row = blockIdx.x * 4 + wave; row < NNODES; row += gridDim.x * 4) {
        float x0 = X[(size_t)row * K + lane];
        float x1 = 0.f;
        if constexpr (K == 128) x1 = X[(size_t)row * K + 64 + lane];
        float al = blv, ar = brv;
#pragma unroll
        for (int k = 0; k < 64; ++k) {
            float xv = __shfl(x0, k, 64);
            al += xv * sWl[k][lane];
            ar += xv * sWr[k][lane];
        }
        if constexpr (K == 128) {
#pragma unroll
            for (int k = 0; k < 64; ++k) {
                float xv = __shfl(x1, k, 64);
                al += xv * sWl[64 + k][lane];
                ar += xv * sWr[64 + k][lane];
            }
        }
        XL[(size_t)row * 64 + lane] = al;
        XR[(size_t)row * 64 + lane] = ar;
    }
}

// ---------------- fused GATv2 edge pass (online softmax, one wave per node) ----------------

__global__ __launch_bounds__(256) void k_edge(const float* __restrict__ XL,
                                              const float* __restrict__ XR,
                                              const int* __restrict__ rowptr,
                                              const int* __restrict__ ssorted,
                                              const float* __restrict__ easorted,
                                              const float* __restrict__ We,
                                              const float* __restrict__ att,
                                              const float* __restrict__ bias,
                                              const float* __restrict__ easum,
                                              float* __restrict__ H) {
    int wave = threadIdx.x >> 6, lane = threadIdx.x & 63;
    float We_l = We[lane], att_l = att[lane], bias_l = bias[lane];
    float ea_mean = easum[0] * (1.0f / NEDGES);
    for (int i = blockIdx.x * 4 + wave; i < NNODES; i += gridDim.x * 4) {
        float xr_l = XR[(size_t)i * 64 + lane];
        float xl_i = XL[(size_t)i * 64 + lane];
        // self-loop edge (src = i, ea = ea_mean)
        float m0 = xl_i + xr_l + ea_mean * We_l;
        m0 = fmaxf(m0, 0.f) + NEG_SLOPE * fminf(m0, 0.f);
        float M = wave_sum64(m0 * att_l);
        float S = 1.f;
        float acc = xl_i;
        int e = rowptr[i], e1 = rowptr[i + 1];
        for (; e < e1; ++e) {
            int s = ssorted[e];
            float eav = easorted[e];
            float v = XL[(size_t)s * 64 + lane];
            float m = v + xr_l + eav * We_l;
            m = fmaxf(m, 0.f) + NEG_SLOPE * fminf(m, 0.f);
            float a = wave_sum64(m * att_l);
            float newM = fmaxf(M, a);
            float sc = __expf(M - newM);
            float p = __expf(a - newM);
            S = S * sc + p;
            acc = acc * sc + p * v;
            M = newM;
        }
        float o = acc / S + bias_l;
        H[(size_t)i * 64 + lane] = fmaxf(o, 0.f);  // fused ReLU
    }
}

// ---------------- tail: mean pool + linear + softmax ----------------

__global__ __launch_bounds__(256) void k_colsum(const float* __restrict__ H,
                                                float* __restrict__ gsum) {
    int wave = threadIdx.x >> 6, lane = threadIdx.x & 63;
    float s = 0.f;
    for (int r = blockIdx.x * 4 + wave; r < NNODES; r += gridDim.x * 4)
        s += H[(size_t)r * 64 + lane];
    __shared__ float ls[4][64];
    ls[wave][lane] = s;
    __syncthreads();
    if (wave == 0) {
        s = ls[0][lane] + ls[1][lane] + ls[2][lane] + ls[3][lane];
        atomicAdd(&gsum[lane], s);
    }
}

__global__ __launch_bounds__(64) void k_head(const float* __restrict__ gsum,
                                             const float* __restrict__ Wlin,
                                             const float* __restrict__ blin,
                                             float* __restrict__ out) {
    int lane = threadIdx.x;
    float g = gsum[lane] * (1.0f / NNODES);
    float a0 = wave_sum64(g * Wlin[lane * 2 + 0]);
    float a1 = wave_sum64(g * Wlin[lane * 2 + 1]);
    if (lane == 0) {
        float l0 = a0 + blin[0], l1 = a1 + blin[1];
        float mx = fmaxf(l0, l1);
        float e0 = __expf(l0 - mx), e1 = __expf(l1 - mx);
        float inv = 1.f / (e0 + e1);
        out[0] = e0 * inv;
        out[1] = e1 * inv;
    }
}

extern "C" void kernel_launch(void* const* d_in, const int* in_sizes, int n_in,
                              void* d_out, int out_size, void* d_ws, size_t ws_size,
                              hipStream_t stream) {
    const float* x = (const float*)d_in[0];
    const int* ei = (const int*)d_in[1];
    const float* ea = (const float*)d_in[2];
    const int* src = ei;
    const int* dst = ei + NEDGES;
    auto W = [&](int i) { return (const float*)d_in[i]; };

    char* ws = (char*)d_ws;
    size_t off = 0;
    auto alloc = [&](size_t bytes) {
        void* p = ws + off;
        off += (bytes + 255) & ~(size_t)255;
        return p;
    };
    float* XLb = (float*)alloc((size_t)NNODES * 64 * 4);
    float* XRb = (float*)alloc((size_t)NNODES * 64 * 4);
    float* Hb = (float*)alloc((size_t)NNODES * 64 * 4);
    int* rowptr = (int*)alloc((size_t)(NNODES + 1) * 4);
    int* cnt = (int*)alloc((size_t)NNODES * 4);
    int* ssorted = (int*)alloc((size_t)NEDGES * 4);
    float* easorted = (float*)alloc((size_t)NEDGES * 4);
    float* easum = (float*)alloc(4);
    float* gsum = (float*)alloc(64 * 4);

    hipMemsetAsync(cnt, 0, (size_t)NNODES * 4, stream);
    hipMemsetAsync(easum, 0, 4, stream);
    hipMemsetAsync(gsum, 0, 64 * 4, stream);

    k_hist<<<2048, 256, 0, stream>>>(dst, ea, cnt, easum);
    k_scan<<<1, 1024, 0, stream>>>(cnt, rowptr);
    hipMemsetAsync(cnt, 0, (size_t)NNODES * 4, stream);  // reuse as scatter cursor
    k_scatter<<<2048, 256, 0, stream>>>(src, dst, ea, rowptr, cnt, ssorted, easorted);

    int edge_grid = (NNODES + 3) / 4;

    // layer 1
    k_gemm<128><<<1024, 256, 0, stream>>>(x, W(3), W(4), W(5), W(6), XLb, XRb);
    k_edge<<<edge_grid, 256, 0, stream>>>(XLb, XRb, rowptr, ssorted, easorted,
                                          W(7), W(8), W(9), easum, Hb);
    // layer 2
    k_gemm<64><<<1024, 256, 0, stream>>>(Hb, W(10), W(11), W(12), W(13), XLb, XRb);
    k_edge<<<edge_grid, 256, 0, stream>>>(XLb, XRb, rowptr, ssorted, easorted,
                                          W(14), W(15), W(16), easum, Hb);
    // layer 3
    k_gemm<64><<<1024, 256, 0, stream>>>(Hb, W(17), W(18), W(19), W(20), XLb, XRb);
    k_edge<<<edge_grid, 256, 0, stream>>>(XLb, XRb, rowptr, ssorted, easorted,
                                          W(21), W(22), W(23), easum, Hb);

    k_colsum<<<1024, 256, 0, stream>>>(Hb, gsum);
    k_head<<<1, 64, 0, stream>>>(gsum, W(24), W(25), (float*)d_out);
}

// Round 2
// 1098.201 us; speedup vs baseline: 1.4452x; 1.4452x over previous
//
#include <hip/hip_runtime.h>
#include <hip/hip_bf16.h>

#define NNODES 100000
#define NEDGES 1600000
#define NEG_SLOPE 0.2f

__device__ __forceinline__ float wave_sum64(float v) {
#pragma unroll
    for (int off = 1; off < 64; off <<= 1) v += __shfl_xor(v, off, 64);
    return v;
}

// ---------------- CSR build ----------------

__global__ __launch_bounds__(256) void k_hist(const int* __restrict__ dst,
                                              const float* __restrict__ ea,
                                              int* __restrict__ cnt,
                                              float* __restrict__ easum) {
    int wave = threadIdx.x >> 6, lane = threadIdx.x & 63;
    float s = 0.f;
    for (int i = blockIdx.x * 256 + threadIdx.x; i < NEDGES; i += gridDim.x * 256) {
        atomicAdd(&cnt[dst[i]], 1);
        s += ea[i];
    }
    s = wave_sum64(s);
    __shared__ float ws[4];
    if (lane == 0) ws[wave] = s;
    __syncthreads();
    if (threadIdx.x == 0) atomicAdd(easum, ws[0] + ws[1] + ws[2] + ws[3]);
}

__global__ __launch_bounds__(1024) void k_scan(const int* __restrict__ cnt,
                                               int* __restrict__ rowptr) {
    __shared__ int part[1024];
    const int n = NNODES;
    int t = threadIdx.x;
    int chunk = (n + 1023) >> 10;
    int lo = t * chunk, hi = min(lo + chunk, n);
    int s = 0;
    for (int i = lo; i < hi; ++i) s += cnt[i];
    part[t] = s;
    __syncthreads();
    for (int off = 1; off < 1024; off <<= 1) {
        int v = (t >= off) ? part[t - off] : 0;
        __syncthreads();
        part[t] += v;
        __syncthreads();
    }
    int run = (t == 0) ? 0 : part[t - 1];
    for (int i = lo; i < hi; ++i) { rowptr[i] = run; run += cnt[i]; }
    if (t == 1023) rowptr[n] = part[1023];
}

__global__ __launch_bounds__(256) void k_scatter(const int* __restrict__ src,
                                                 const int* __restrict__ dst,
                                                 const float* __restrict__ ea,
                                                 const int* __restrict__ rowptr,
                                                 int* __restrict__ cursor,
                                                 int* __restrict__ ssorted,
                                                 float* __restrict__ easorted) {
    for (int i = blockIdx.x * 256 + threadIdx.x; i < NEDGES; i += gridDim.x * 256) {
        int d = dst[i];
        int pos = rowptr[d] + atomicAdd(&cursor[d], 1);
        ssorted[pos] = src[i];
        easorted[pos] = ea[i];
    }
}

// ---------------- register-tiled dual GEMM: [XL|XR] = X @ [Wl|Wr] + [bl|br] ----------------
// 128x128 output tile per block, 8x8 per thread, K chunked by 32.
// sX stored transposed [k][row] with pad (stride 132: conflict-free + 16B aligned).

template <int K>
__global__ __launch_bounds__(256) void k_gemm(const float* __restrict__ X,
                                              const float* __restrict__ Wl,
                                              const float* __restrict__ bl,
                                              const float* __restrict__ Wr,
                                              const float* __restrict__ br,
                                              float* __restrict__ XL,
                                              float* __restrict__ XR) {
    constexpr int KC = 32;
    __shared__ float sX[KC][132];
    __shared__ float sW[KC][128];
    const int t = threadIdx.x;
    const int tc = t & 15, tr = t >> 4;      // 16 col-threads x 16 row-threads
    const int r0 = blockIdx.x * 128;

    float acc[8][8] = {};

    for (int kc = 0; kc < K; kc += KC) {
        // stage X chunk (transposed): 128 rows x 32 k
#pragma unroll
        for (int i = 0; i < 4; ++i) {
            int l = t + 256 * i;
            int row = l >> 3;
            int kq = (l & 7) * 4;
            int rr = min(r0 + row, NNODES - 1);
            const float4 v = *(const float4*)&X[(size_t)rr * K + kc + kq];
            sX[kq + 0][row] = v.x;
            sX[kq + 1][row] = v.y;
            sX[kq + 2][row] = v.z;
            sX[kq + 3][row] = v.w;
        }
        // stage W chunk: 32 k x 128 cols ([Wl | Wr])
#pragma unroll
        for (int i = 0; i < 4; ++i) {
            int l = t + 256 * i;
            int k = l >> 5;
            int cq = l & 31;
            const float* sp = (cq < 16) ? &Wl[(size_t)(kc + k) * 64 + cq * 4]
                                        : &Wr[(size_t)(kc + k) * 64 + (cq - 16) * 4];
            *(float4*)&sW[k][cq * 4] = *(const float4*)sp;
        }
        __syncthreads();
#pragma unroll 4
        for (int k = 0; k < KC; ++k) {
            float xf[8], wf[8];
            *(float4*)&xf[0] = *(const float4*)&sX[k][tr * 8];
            *(float4*)&xf[4] = *(const float4*)&sX[k][tr * 8 + 4];
            *(float4*)&wf[0] = *(const float4*)&sW[k][tc * 8];
            *(float4*)&wf[4] = *(const float4*)&sW[k][tc * 8 + 4];
#pragma unroll
            for (int i2 = 0; i2 < 8; ++i2)
#pragma unroll
                for (int j = 0; j < 8; ++j)
                    acc[i2][j] += xf[i2] * wf[j];
        }
        __syncthreads();
    }

    // epilogue: bias + store (each thread's 8 cols are entirely in XL or XR)
    const bool isL = (tc < 8);
    const int cb = isL ? tc * 8 : tc * 8 - 64;
    const float* bb = isL ? bl : br;
    float* OUT = isL ? XL : XR;
    float4 b0 = *(const float4*)&bb[cb];
    float4 b1 = *(const float4*)&bb[cb + 4];
#pragma unroll
    for (int i = 0; i < 8; ++i) {
        int row = r0 + tr * 8 + i;
        if (row < NNODES) {
            float4 v0 = {acc[i][0] + b0.x, acc[i][1] + b0.y, acc[i][2] + b0.z, acc[i][3] + b0.w};
            float4 v1 = {acc[i][4] + b1.x, acc[i][5] + b1.y, acc[i][6] + b1.z, acc[i][7] + b1.w};
            *(float4*)&OUT[(size_t)row * 64 + cb] = v0;
            *(float4*)&OUT[(size_t)row * 64 + cb + 4] = v1;
        }
    }
}

// ---------------- fused GATv2 edge pass (online softmax, one wave per node) ----------------

__global__ __launch_bounds__(256) void k_edge(const float* __restrict__ XL,
                                              const float* __restrict__ XR,
                                              const int* __restrict__ rowptr,
                                              const int* __restrict__ ssorted,
                                              const float* __restrict__ easorted,
                                              const float* __restrict__ We,
                                              const float* __restrict__ att,
                                              const float* __restrict__ bias,
                                              const float* __restrict__ easum,
                                              float* __restrict__ H) {
    int wave = threadIdx.x >> 6, lane = threadIdx.x & 63;
    float We_l = We[lane], att_l = att[lane], bias_l = bias[lane];
    float ea_mean = easum[0] * (1.0f / NEDGES);
    for (int i = blockIdx.x * 4 + wave; i < NNODES; i += gridDim.x * 4) {
        float xr_l = XR[(size_t)i * 64 + lane];
        float xl_i = XL[(size_t)i * 64 + lane];
        // self-loop edge (src = i, ea = ea_mean)
        float m0 = xl_i + xr_l + ea_mean * We_l;
        m0 = fmaxf(m0, 0.f) + NEG_SLOPE * fminf(m0, 0.f);
        float M = wave_sum64(m0 * att_l);
        float S = 1.f;
        float acc = xl_i;
        int e = rowptr[i], e1 = rowptr[i + 1];
        for (; e < e1; ++e) {
            int s = ssorted[e];
            float eav = easorted[e];
            float v = XL[(size_t)s * 64 + lane];
            float m = v + xr_l + eav * We_l;
            m = fmaxf(m, 0.f) + NEG_SLOPE * fminf(m, 0.f);
            float a = wave_sum64(m * att_l);
            float newM = fmaxf(M, a);
            float sc = __expf(M - newM);
            float p = __expf(a - newM);
            S = S * sc + p;
            acc = acc * sc + p * v;
            M = newM;
        }
        float o = acc / S + bias_l;
        H[(size_t)i * 64 + lane] = fmaxf(o, 0.f);  // fused ReLU
    }
}

// ---------------- tail: mean pool + linear + softmax ----------------

__global__ __launch_bounds__(256) void k_colsum(const float* __restrict__ H,
                                                float* __restrict__ gsum) {
    int wave = threadIdx.x >> 6, lane = threadIdx.x & 63;
    float s = 0.f;
    for (int r = blockIdx.x * 4 + wave; r < NNODES; r += gridDim.x * 4)
        s += H[(size_t)r * 64 + lane];
    __shared__ float ls[4][64];
    ls[wave][lane] = s;
    __syncthreads();
    if (wave == 0) {
        s = ls[0][lane] + ls[1][lane] + ls[2][lane] + ls[3][lane];
        atomicAdd(&gsum[lane], s);
    }
}

__global__ __launch_bounds__(64) void k_head(const float* __restrict__ gsum,
                                             const float* __restrict__ Wlin,
                                             const float* __restrict__ blin,
                                             float* __restrict__ out) {
    int lane = threadIdx.x;
    float g = gsum[lane] * (1.0f / NNODES);
    float a0 = wave_sum64(g * Wlin[lane * 2 + 0]);
    float a1 = wave_sum64(g * Wlin[lane * 2 + 1]);
    if (lane == 0) {
        float l0 = a0 + blin[0], l1 = a1 + blin[1];
        float mx = fmaxf(l0, l1);
        float e0 = __expf(l0 - mx), e1 = __expf(l1 - mx);
        float inv = 1.f / (e0 + e1);
        out[0] = e0 * inv;
        out[1] = e1 * inv;
    }
}

extern "C" void kernel_launch(void* const* d_in, const int* in_sizes, int n_in,
                              void* d_out, int out_size, void* d_ws, size_t ws_size,
                              hipStream_t stream) {
    const float* x = (const float*)d_in[0];
    const int* ei = (const int*)d_in[1];
    const float* ea = (const float*)d_in[2];
    const int* src = ei;
    const int* dst = ei + NEDGES;
    auto W = [&](int i) { return (const float*)d_in[i]; };

    char* ws = (char*)d_ws;
    size_t off = 0;
    auto alloc = [&](size_t bytes) {
        void* p = ws + off;
        off += (bytes + 255) & ~(size_t)255;
        return p;
    };
    float* XLb = (float*)alloc((size_t)NNODES * 64 * 4);
    float* XRb = (float*)alloc((size_t)NNODES * 64 * 4);
    float* Hb = (float*)alloc((size_t)NNODES * 64 * 4);
    int* rowptr = (int*)alloc((size_t)(NNODES + 1) * 4);
    int* cnt = (int*)alloc((size_t)NNODES * 4);
    int* ssorted = (int*)alloc((size_t)NEDGES * 4);
    float* easorted = (float*)alloc((size_t)NEDGES * 4);
    float* easum = (float*)alloc(4);
    float* gsum = (float*)alloc(64 * 4);

    hipMemsetAsync(cnt, 0, (size_t)NNODES * 4, stream);
    hipMemsetAsync(easum, 0, 4, stream);
    hipMemsetAsync(gsum, 0, 64 * 4, stream);

    k_hist<<<2048, 256, 0, stream>>>(dst, ea, cnt, easum);
    k_scan<<<1, 1024, 0, stream>>>(cnt, rowptr);
    hipMemsetAsync(cnt, 0, (size_t)NNODES * 4, stream);  // reuse as scatter cursor
    k_scatter<<<2048, 256, 0, stream>>>(src, dst, ea, rowptr, cnt, ssorted, easorted);

    int gemm_grid = (NNODES + 127) / 128;
    int edge_grid = (NNODES + 3) / 4;

    // layer 1
    k_gemm<128><<<gemm_grid, 256, 0, stream>>>(x, W(3), W(4), W(5), W(6), XLb, XRb);
    k_edge<<<edge_grid, 256, 0, stream>>>(XLb, XRb, rowptr, ssorted, easorted,
                                          W(7), W(8), W(9), easum, Hb);
    // layer 2
    k_gemm<64><<<gemm_grid, 256, 0, stream>>>(Hb, W(10), W(11), W(12), W(13), XLb, XRb);
    k_edge<<<edge_grid, 256, 0, stream>>>(XLb, XRb, rowptr, ssorted, easorted,
                                          W(14), W(15), W(16), easum, Hb);
    // layer 3
    k_gemm<64><<<gemm_grid, 256, 0, stream>>>(Hb, W(17), W(18), W(19), W(20), XLb, XRb);
    k_edge<<<edge_grid, 256, 0, stream>>>(XLb, XRb, rowptr, ssorted, easorted,
                                          W(21), W(22), W(23), easum, Hb);

    k_colsum<<<1024, 256, 0, stream>>>(Hb, gsum);
    k_head<<<1, 64, 0, stream>>>(gsum, W(24), W(25), (float*)d_out);
}

// Round 3
// 782.514 us; speedup vs baseline: 2.0282x; 1.4034x over previous
//
#include <hip/hip_runtime.h>
#include <hip/hip_bf16.h>

#define NNODES 100000
#define NEDGES 1600000
#define NEG_SLOPE 0.2f

__device__ __forceinline__ float wave_sum64(float v) {
#pragma unroll
    for (int off = 1; off < 64; off <<= 1) v += __shfl_xor(v, off, 64);
    return v;
}

// ---------------- CSR build ----------------

__global__ __launch_bounds__(256) void k_hist(const int* __restrict__ dst,
                                              const float* __restrict__ ea,
                                              int* __restrict__ cnt,
                                              float* __restrict__ easum) {
    int wave = threadIdx.x >> 6, lane = threadIdx.x & 63;
    float s = 0.f;
    for (int i = blockIdx.x * 256 + threadIdx.x; i < NEDGES; i += gridDim.x * 256) {
        atomicAdd(&cnt[dst[i]], 1);
        s += ea[i];
    }
    s = wave_sum64(s);
    __shared__ float ws[4];
    if (lane == 0) ws[wave] = s;
    __syncthreads();
    if (threadIdx.x == 0) atomicAdd(easum, ws[0] + ws[1] + ws[2] + ws[3]);
}

__global__ __launch_bounds__(1024) void k_scan(const int* __restrict__ cnt,
                                               int* __restrict__ rowptr) {
    __shared__ int part[1024];
    const int n = NNODES;
    int t = threadIdx.x;
    int chunk = (n + 1023) >> 10;
    int lo = t * chunk, hi = min(lo + chunk, n);
    int s = 0;
    for (int i = lo; i < hi; ++i) s += cnt[i];
    part[t] = s;
    __syncthreads();
    for (int off = 1; off < 1024; off <<= 1) {
        int v = (t >= off) ? part[t - off] : 0;
        __syncthreads();
        part[t] += v;
        __syncthreads();
    }
    int run = (t == 0) ? 0 : part[t - 1];
    for (int i = lo; i < hi; ++i) { rowptr[i] = run; run += cnt[i]; }
    if (t == 1023) rowptr[n] = part[1023];
}

__global__ __launch_bounds__(256) void k_scatter(const int* __restrict__ src,
                                                 const int* __restrict__ dst,
                                                 const float* __restrict__ ea,
                                                 const int* __restrict__ rowptr,
                                                 int* __restrict__ cursor,
                                                 int* __restrict__ ssorted,
                                                 float* __restrict__ easorted) {
    for (int i = blockIdx.x * 256 + threadIdx.x; i < NEDGES; i += gridDim.x * 256) {
        int d = dst[i];
        int pos = rowptr[d] + atomicAdd(&cursor[d], 1);
        ssorted[pos] = src[i];
        easorted[pos] = ea[i];
    }
}

// ---------------- register-tiled dual GEMM: [XL|XR] = X @ [Wl|Wr] + [bl|br] ----------------

template <int K>
__global__ __launch_bounds__(256) void k_gemm(const float* __restrict__ X,
                                              const float* __restrict__ Wl,
                                              const float* __restrict__ bl,
                                              const float* __restrict__ Wr,
                                              const float* __restrict__ br,
                                              float* __restrict__ XL,
                                              float* __restrict__ XR) {
    constexpr int KC = 32;
    __shared__ float sX[KC][132];
    __shared__ float sW[KC][128];
    const int t = threadIdx.x;
    const int tc = t & 15, tr = t >> 4;
    const int r0 = blockIdx.x * 128;

    float acc[8][8] = {};

    for (int kc = 0; kc < K; kc += KC) {
#pragma unroll
        for (int i = 0; i < 4; ++i) {
            int l = t + 256 * i;
            int row = l >> 3;
            int kq = (l & 7) * 4;
            int rr = min(r0 + row, NNODES - 1);
            const float4 v = *(const float4*)&X[(size_t)rr * K + kc + kq];
            sX[kq + 0][row] = v.x;
            sX[kq + 1][row] = v.y;
            sX[kq + 2][row] = v.z;
            sX[kq + 3][row] = v.w;
        }
#pragma unroll
        for (int i = 0; i < 4; ++i) {
            int l = t + 256 * i;
            int k = l >> 5;
            int cq = l & 31;
            const float* sp = (cq < 16) ? &Wl[(size_t)(kc + k) * 64 + cq * 4]
                                        : &Wr[(size_t)(kc + k) * 64 + (cq - 16) * 4];
            *(float4*)&sW[k][cq * 4] = *(const float4*)sp;
        }
        __syncthreads();
#pragma unroll 4
        for (int k = 0; k < KC; ++k) {
            float xf[8], wf[8];
            *(float4*)&xf[0] = *(const float4*)&sX[k][tr * 8];
            *(float4*)&xf[4] = *(const float4*)&sX[k][tr * 8 + 4];
            *(float4*)&wf[0] = *(const float4*)&sW[k][tc * 8];
            *(float4*)&wf[4] = *(const float4*)&sW[k][tc * 8 + 4];
#pragma unroll
            for (int i2 = 0; i2 < 8; ++i2)
#pragma unroll
                for (int j = 0; j < 8; ++j)
                    acc[i2][j] += xf[i2] * wf[j];
        }
        __syncthreads();
    }

    const bool isL = (tc < 8);
    const int cb = isL ? tc * 8 : tc * 8 - 64;
    const float* bb = isL ? bl : br;
    float* OUT = isL ? XL : XR;
    float4 b0 = *(const float4*)&bb[cb];
    float4 b1 = *(const float4*)&bb[cb + 4];
#pragma unroll
    for (int i = 0; i < 8; ++i) {
        int row = r0 + tr * 8 + i;
        if (row < NNODES) {
            float4 v0 = {acc[i][0] + b0.x, acc[i][1] + b0.y, acc[i][2] + b0.z, acc[i][3] + b0.w};
            float4 v1 = {acc[i][4] + b1.x, acc[i][5] + b1.y, acc[i][6] + b1.z, acc[i][7] + b1.w};
            *(float4*)&OUT[(size_t)row * 64 + cb] = v0;
            *(float4*)&OUT[(size_t)row * 64 + cb + 4] = v1;
        }
    }
}

// ---------------- fused GATv2 edge pass ----------------
// One wave per node. Lane layout: lane = 16*group + fl; group g in [0,4) handles
// edge e+g; lane holds features [fl*4, fl*4+4) as float4. Online softmax merged
// 4 edges at a time (exact).

__global__ __launch_bounds__(256) void k_edge(const float* __restrict__ XL,
                                              const float* __restrict__ XR,
                                              const int* __restrict__ rowptr,
                                              const int* __restrict__ ssorted,
                                              const float* __restrict__ easorted,
                                              const float* __restrict__ We,
                                              const float* __restrict__ att,
                                              const float* __restrict__ bias,
                                              const float* __restrict__ easum,
                                              float* __restrict__ H) {
    const int wave = threadIdx.x >> 6, lane = threadIdx.x & 63;
    const int g = lane >> 4, fl = lane & 15;
    const int fo = fl * 4;
    const float4 We4 = *(const float4*)&We[fo];
    const float4 att4 = *(const float4*)&att[fo];
    const float4 bias4 = *(const float4*)&bias[fo];
    const float ea_mean = easum[0] * (1.0f / NEDGES);

    for (int i = blockIdx.x * 4 + wave; i < NNODES; i += gridDim.x * 4) {
        const float4 xr4 = *(const float4*)&XR[(size_t)i * 64 + fo];
        const float4 xl4 = *(const float4*)&XL[(size_t)i * 64 + fo];

        // self-loop (src=i, ea=ea_mean), computed identically in all groups
        float mx = xl4.x + xr4.x + ea_mean * We4.x;
        float my = xl4.y + xr4.y + ea_mean * We4.y;
        float mz = xl4.z + xr4.z + ea_mean * We4.z;
        float mw = xl4.w + xr4.w + ea_mean * We4.w;
        mx = fmaxf(mx, 0.f) + NEG_SLOPE * fminf(mx, 0.f);
        my = fmaxf(my, 0.f) + NEG_SLOPE * fminf(my, 0.f);
        mz = fmaxf(mz, 0.f) + NEG_SLOPE * fminf(mz, 0.f);
        mw = fmaxf(mw, 0.f) + NEG_SLOPE * fminf(mw, 0.f);
        float part = mx * att4.x + my * att4.y + mz * att4.z + mw * att4.w;
        part += __shfl_xor(part, 1);
        part += __shfl_xor(part, 2);
        part += __shfl_xor(part, 4);
        part += __shfl_xor(part, 8);
        float M = part;          // a_self, uniform across wave
        float S = 1.f;
        float ax = (g == 0) ? xl4.x : 0.f;   // acc (group-replicated sum at end)
        float ay = (g == 0) ? xl4.y : 0.f;
        float az = (g == 0) ? xl4.z : 0.f;
        float aw = (g == 0) ? xl4.w : 0.f;

        const int e0 = rowptr[i], e1 = rowptr[i + 1];
        for (int e = e0; e < e1; e += 4) {
            const int eidx = e + g;
            const bool valid = eidx < e1;
            const int s = valid ? ssorted[eidx] : 0;
            const float eav = valid ? easorted[eidx] : 0.f;
            const float4 v4 = *(const float4*)&XL[(size_t)s * 64 + fo];

            float bx = v4.x + xr4.x + eav * We4.x;
            float by = v4.y + xr4.y + eav * We4.y;
            float bz = v4.z + xr4.z + eav * We4.z;
            float bw = v4.w + xr4.w + eav * We4.w;
            bx = fmaxf(bx, 0.f) + NEG_SLOPE * fminf(bx, 0.f);
            by = fmaxf(by, 0.f) + NEG_SLOPE * fminf(by, 0.f);
            bz = fmaxf(bz, 0.f) + NEG_SLOPE * fminf(bz, 0.f);
            bw = fmaxf(bw, 0.f) + NEG_SLOPE * fminf(bw, 0.f);
            float d = bx * att4.x + by * att4.y + bz * att4.z + bw * att4.w;
            d += __shfl_xor(d, 1);
            d += __shfl_xor(d, 2);
            d += __shfl_xor(d, 4);
            d += __shfl_xor(d, 8);
            float a = valid ? d : -1e30f;          // group-uniform logit

            float am = fmaxf(a, __shfl_xor(a, 16));
            am = fmaxf(am, __shfl_xor(am, 32));    // max over 4 edges
            const float newM = fmaxf(M, am);
            const float sc = __expf(M - newM);
            const float p = __expf(a - newM);      // 0 for invalid groups
            float ps = p;
            ps += __shfl_xor(ps, 16);
            ps += __shfl_xor(ps, 32);              // sum p over groups
            S = S * sc + ps;
            ax = ax * sc + p * v4.x;
            ay = ay * sc + p * v4.y;
            az = az * sc + p * v4.z;
            aw = aw * sc + p * v4.w;
            M = newM;
        }

        // combine the 4 group-partial accumulators
        ax += __shfl_xor(ax, 16); ax += __shfl_xor(ax, 32);
        ay += __shfl_xor(ay, 16); ay += __shfl_xor(ay, 32);
        az += __shfl_xor(az, 16); az += __shfl_xor(az, 32);
        aw += __shfl_xor(aw, 16); aw += __shfl_xor(aw, 32);

        if (g == 0) {
            const float invS = 1.0f / S;
            float4 o;
            o.x = fmaxf(ax * invS + bias4.x, 0.f);
            o.y = fmaxf(ay * invS + bias4.y, 0.f);
            o.z = fmaxf(az * invS + bias4.z, 0.f);
            o.w = fmaxf(aw * invS + bias4.w, 0.f);
            *(float4*)&H[(size_t)i * 64 + fo] = o;
        }
    }
}

// ---------------- tail: mean pool + linear + softmax ----------------

__global__ __launch_bounds__(256) void k_colsum(const float* __restrict__ H,
                                                float* __restrict__ gsum) {
    int wave = threadIdx.x >> 6, lane = threadIdx.x & 63;
    float s = 0.f;
    for (int r = blockIdx.x * 4 + wave; r < NNODES; r += gridDim.x * 4)
        s += H[(size_t)r * 64 + lane];
    __shared__ float ls[4][64];
    ls[wave][lane] = s;
    __syncthreads();
    if (wave == 0) {
        s = ls[0][lane] + ls[1][lane] + ls[2][lane] + ls[3][lane];
        atomicAdd(&gsum[lane], s);
    }
}

__global__ __launch_bounds__(64) void k_head(const float* __restrict__ gsum,
                                             const float* __restrict__ Wlin,
                                             const float* __restrict__ blin,
                                             float* __restrict__ out) {
    int lane = threadIdx.x;
    float g = gsum[lane] * (1.0f / NNODES);
    float a0 = wave_sum64(g * Wlin[lane * 2 + 0]);
    float a1 = wave_sum64(g * Wlin[lane * 2 + 1]);
    if (lane == 0) {
        float l0 = a0 + blin[0], l1 = a1 + blin[1];
        float mx = fmaxf(l0, l1);
        float e0 = __expf(l0 - mx), e1 = __expf(l1 - mx);
        float inv = 1.f / (e0 + e1);
        out[0] = e0 * inv;
        out[1] = e1 * inv;
    }
}

extern "C" void kernel_launch(void* const* d_in, const int* in_sizes, int n_in,
                              void* d_out, int out_size, void* d_ws, size_t ws_size,
                              hipStream_t stream) {
    const float* x = (const float*)d_in[0];
    const int* ei = (const int*)d_in[1];
    const float* ea = (const float*)d_in[2];
    const int* src = ei;
    const int* dst = ei + NEDGES;
    auto W = [&](int i) { return (const float*)d_in[i]; };

    char* ws = (char*)d_ws;
    size_t off = 0;
    auto alloc = [&](size_t bytes) {
        void* p = ws + off;
        off += (bytes + 255) & ~(size_t)255;
        return p;
    };
    float* XLb = (float*)alloc((size_t)NNODES * 64 * 4);
    float* XRb = (float*)alloc((size_t)NNODES * 64 * 4);
    float* Hb = (float*)alloc((size_t)NNODES * 64 * 4);
    int* rowptr = (int*)alloc((size_t)(NNODES + 1) * 4);
    int* cnt = (int*)alloc((size_t)NNODES * 4);
    int* ssorted = (int*)alloc((size_t)NEDGES * 4);
    float* easorted = (float*)alloc((size_t)NEDGES * 4);
    float* easum = (float*)alloc(4);
    float* gsum = (float*)alloc(64 * 4);

    hipMemsetAsync(cnt, 0, (size_t)NNODES * 4, stream);
    hipMemsetAsync(easum, 0, 4, stream);
    hipMemsetAsync(gsum, 0, 64 * 4, stream);

    k_hist<<<2048, 256, 0, stream>>>(dst, ea, cnt, easum);
    k_scan<<<1, 1024, 0, stream>>>(cnt, rowptr);
    hipMemsetAsync(cnt, 0, (size_t)NNODES * 4, stream);
    k_scatter<<<2048, 256, 0, stream>>>(src, dst, ea, rowptr, cnt, ssorted, easorted);

    int gemm_grid = (NNODES + 127) / 128;
    int edge_grid = (NNODES + 3) / 4;

    k_gemm<128><<<gemm_grid, 256, 0, stream>>>(x, W(3), W(4), W(5), W(6), XLb, XRb);
    k_edge<<<edge_grid, 256, 0, stream>>>(XLb, XRb, rowptr, ssorted, easorted,
                                          W(7), W(8), W(9), easum, Hb);
    k_gemm<64><<<gemm_grid, 256, 0, stream>>>(Hb, W(10), W(11), W(12), W(13), XLb, XRb);
    k_edge<<<edge_grid, 256, 0, stream>>>(XLb, XRb, rowptr, ssorted, easorted,
                                          W(14), W(15), W(16), easum, Hb);
    k_gemm<64><<<gemm_grid, 256, 0, stream>>>(Hb, W(17), W(18), W(19), W(20), XLb, XRb);
    k_edge<<<edge_grid, 256, 0, stream>>>(XLb, XRb, rowptr, ssorted, easorted,
                                          W(21), W(22), W(23), easum, Hb);

    k_colsum<<<1024, 256, 0, stream>>>(Hb, gsum);
    k_head<<<1, 64, 0, stream>>>(gsum, W(24), W(25), (float*)d_out);
}

// Round 4
// 638.320 us; speedup vs baseline: 2.4864x; 1.2259x over previous
//
#include <hip/hip_runtime.h>
#include <hip/hip_bf16.h>

#define NNODES 100000
#define NEDGES 1600000
#define NEG_SLOPE 0.2f
#define SCAN_BLOCKS ((NNODES + 255) / 256)   // 391

__device__ __forceinline__ float wave_sum64(float v) {
#pragma unroll
    for (int off = 1; off < 64; off <<= 1) v += __shfl_xor(v, off, 64);
    return v;
}

__device__ __forceinline__ int wave_sum64i(int v) {
#pragma unroll
    for (int off = 1; off < 64; off <<= 1) v += __shfl_xor(v, off, 64);
    return v;
}

// ---------------- CSR build ----------------

__global__ __launch_bounds__(256) void k_hist(const int* __restrict__ dst,
                                              const float* __restrict__ ea,
                                              int* __restrict__ cnt,
                                              float* __restrict__ easum) {
    int wave = threadIdx.x >> 6, lane = threadIdx.x & 63;
    float s = 0.f;
    for (int i = blockIdx.x * 256 + threadIdx.x; i < NEDGES; i += gridDim.x * 256) {
        atomicAdd(&cnt[dst[i]], 1);
        s += ea[i];
    }
    s = wave_sum64(s);
    __shared__ float ws[4];
    if (lane == 0) ws[wave] = s;
    __syncthreads();
    if (threadIdx.x == 0) atomicAdd(easum, ws[0] + ws[1] + ws[2] + ws[3]);
}

// ---- device-wide exclusive scan of cnt[NNODES] -> rowptr, 3 dispatches ----

__global__ __launch_bounds__(256) void k_partial(const int* __restrict__ cnt,
                                                 int* __restrict__ bsum) {
    int i = blockIdx.x * 256 + threadIdx.x;
    int lane = threadIdx.x & 63, wave = threadIdx.x >> 6;
    int v = (i < NNODES) ? cnt[i] : 0;
    v = wave_sum64i(v);
    __shared__ int ws[4];
    if (lane == 0) ws[wave] = v;
    __syncthreads();
    if (threadIdx.x == 0) bsum[blockIdx.x] = ws[0] + ws[1] + ws[2] + ws[3];
}

__global__ __launch_bounds__(512) void k_scanb(const int* __restrict__ bsum,
                                               int* __restrict__ boff,
                                               int* __restrict__ rowptr) {
    __shared__ int sh[512];
    int t = threadIdx.x;
    int v = (t < SCAN_BLOCKS) ? bsum[t] : 0;
    sh[t] = v;
    __syncthreads();
    for (int off = 1; off < 512; off <<= 1) {
        int u = (t >= off) ? sh[t - off] : 0;
        __syncthreads();
        sh[t] += u;
        __syncthreads();
    }
    if (t < SCAN_BLOCKS) boff[t] = sh[t] - v;   // exclusive block offset
    if (t == SCAN_BLOCKS - 1) rowptr[NNODES] = sh[t];
}

__global__ __launch_bounds__(256) void k_scanfin(const int* __restrict__ cnt,
                                                 const int* __restrict__ boff,
                                                 int* __restrict__ rowptr) {
    int t = threadIdx.x, lane = t & 63, wave = t >> 6;
    int i = blockIdx.x * 256 + t;
    int x = (i < NNODES) ? cnt[i] : 0;
    int orig = x;
#pragma unroll
    for (int off = 1; off < 64; off <<= 1) {
        int u = __shfl_up(x, off, 64);
        if (lane >= off) x += u;
    }
    __shared__ int ws[4];
    if (lane == 63) ws[wave] = x;
    __syncthreads();
    int wexc = 0;
    for (int w = 0; w < wave; ++w) wexc += ws[w];
    if (i < NNODES) rowptr[i] = boff[blockIdx.x] + wexc + x - orig;
}

__global__ __launch_bounds__(256) void k_scatter(const int* __restrict__ src,
                                                 const int* __restrict__ dst,
                                                 const float* __restrict__ ea,
                                                 const int* __restrict__ rowptr,
                                                 int* __restrict__ cursor,
                                                 int* __restrict__ ssorted,
                                                 float* __restrict__ easorted) {
    for (int i = blockIdx.x * 256 + threadIdx.x; i < NEDGES; i += gridDim.x * 256) {
        int d = dst[i];
        int pos = rowptr[d] + atomicAdd(&cursor[d], 1);
        ssorted[pos] = src[i];
        easorted[pos] = ea[i];
    }
}

// ---------------- register-tiled dual GEMM: [XL|XR] = X @ [Wl|Wr] + [bl|br] ----------------

template <int K>
__global__ __launch_bounds__(256) void k_gemm(const float* __restrict__ X,
                                              const float* __restrict__ Wl,
                                              const float* __restrict__ bl,
                                              const float* __restrict__ Wr,
                                              const float* __restrict__ br,
                                              float* __restrict__ XL,
                                              float* __restrict__ XR) {
    constexpr int KC = 32;
    __shared__ float sX[KC][132];
    __shared__ float sW[KC][128];
    const int t = threadIdx.x;
    const int tc = t & 15, tr = t >> 4;
    const int r0 = blockIdx.x * 128;

    float acc[8][8] = {};

    for (int kc = 0; kc < K; kc += KC) {
#pragma unroll
        for (int i = 0; i < 4; ++i) {
            int l = t + 256 * i;
            int row = l >> 3;
            int kq = (l & 7) * 4;
            int rr = min(r0 + row, NNODES - 1);
            const float4 v = *(const float4*)&X[(size_t)rr * K + kc + kq];
            sX[kq + 0][row] = v.x;
            sX[kq + 1][row] = v.y;
            sX[kq + 2][row] = v.z;
            sX[kq + 3][row] = v.w;
        }
#pragma unroll
        for (int i = 0; i < 4; ++i) {
            int l = t + 256 * i;
            int k = l >> 5;
            int cq = l & 31;
            const float* sp = (cq < 16) ? &Wl[(size_t)(kc + k) * 64 + cq * 4]
                                        : &Wr[(size_t)(kc + k) * 64 + (cq - 16) * 4];
            *(float4*)&sW[k][cq * 4] = *(const float4*)sp;
        }
        __syncthreads();
#pragma unroll 4
        for (int k = 0; k < KC; ++k) {
            float xf[8], wf[8];
            *(float4*)&xf[0] = *(const float4*)&sX[k][tr * 8];
            *(float4*)&xf[4] = *(const float4*)&sX[k][tr * 8 + 4];
            *(float4*)&wf[0] = *(const float4*)&sW[k][tc * 8];
            *(float4*)&wf[4] = *(const float4*)&sW[k][tc * 8 + 4];
#pragma unroll
            for (int i2 = 0; i2 < 8; ++i2)
#pragma unroll
                for (int j = 0; j < 8; ++j)
                    acc[i2][j] += xf[i2] * wf[j];
        }
        __syncthreads();
    }

    const bool isL = (tc < 8);
    const int cb = isL ? tc * 8 : tc * 8 - 64;
    const float* bb = isL ? bl : br;
    float* OUT = isL ? XL : XR;
    float4 b0 = *(const float4*)&bb[cb];
    float4 b1 = *(const float4*)&bb[cb + 4];
#pragma unroll
    for (int i = 0; i < 8; ++i) {
        int row = r0 + tr * 8 + i;
        if (row < NNODES) {
            float4 v0 = {acc[i][0] + b0.x, acc[i][1] + b0.y, acc[i][2] + b0.z, acc[i][3] + b0.w};
            float4 v1 = {acc[i][4] + b1.x, acc[i][5] + b1.y, acc[i][6] + b1.z, acc[i][7] + b1.w};
            *(float4*)&OUT[(size_t)row * 64 + cb] = v0;
            *(float4*)&OUT[(size_t)row * 64 + cb + 4] = v1;
        }
    }
}

// ---------------- fused GATv2 edge pass ----------------
// One wave per node. lane = 16*group + fl; group g handles edge e+g;
// lane holds features [fl*4, fl*4+4) as float4. Online softmax, 4 edges/iter.

__global__ __launch_bounds__(256) void k_edge(const float* __restrict__ XL,
                                              const float* __restrict__ XR,
                                              const int* __restrict__ rowptr,
                                              const int* __restrict__ ssorted,
                                              const float* __restrict__ easorted,
                                              const float* __restrict__ We,
                                              const float* __restrict__ att,
                                              const float* __restrict__ bias,
                                              const float* __restrict__ easum,
                                              float* __restrict__ H) {
    const int wave = threadIdx.x >> 6, lane = threadIdx.x & 63;
    const int g = lane >> 4, fl = lane & 15;
    const int fo = fl * 4;
    const float4 We4 = *(const float4*)&We[fo];
    const float4 att4 = *(const float4*)&att[fo];
    const float4 bias4 = *(const float4*)&bias[fo];
    const float ea_mean = easum[0] * (1.0f / NEDGES);

    for (int i = blockIdx.x * 4 + wave; i < NNODES; i += gridDim.x * 4) {
        const float4 xr4 = *(const float4*)&XR[(size_t)i * 64 + fo];
        const float4 xl4 = *(const float4*)&XL[(size_t)i * 64 + fo];

        float mx = xl4.x + xr4.x + ea_mean * We4.x;
        float my = xl4.y + xr4.y + ea_mean * We4.y;
        float mz = xl4.z + xr4.z + ea_mean * We4.z;
        float mw = xl4.w + xr4.w + ea_mean * We4.w;
        mx = fmaxf(mx, 0.f) + NEG_SLOPE * fminf(mx, 0.f);
        my = fmaxf(my, 0.f) + NEG_SLOPE * fminf(my, 0.f);
        mz = fmaxf(mz, 0.f) + NEG_SLOPE * fminf(mz, 0.f);
        mw = fmaxf(mw, 0.f) + NEG_SLOPE * fminf(mw, 0.f);
        float part = mx * att4.x + my * att4.y + mz * att4.z + mw * att4.w;
        part += __shfl_xor(part, 1);
        part += __shfl_xor(part, 2);
        part += __shfl_xor(part, 4);
        part += __shfl_xor(part, 8);
        float M = part;
        float S = 1.f;
        float ax = (g == 0) ? xl4.x : 0.f;
        float ay = (g == 0) ? xl4.y : 0.f;
        float az = (g == 0) ? xl4.z : 0.f;
        float aw = (g == 0) ? xl4.w : 0.f;

        const int e0 = rowptr[i], e1 = rowptr[i + 1];
        for (int e = e0; e < e1; e += 4) {
            const int eidx = e + g;
            const bool valid = eidx < e1;
            const int s = valid ? ssorted[eidx] : 0;
            const float eav = valid ? easorted[eidx] : 0.f;
            const float4 v4 = *(const float4*)&XL[(size_t)s * 64 + fo];

            float bx = v4.x + xr4.x + eav * We4.x;
            float by = v4.y + xr4.y + eav * We4.y;
            float bz = v4.z + xr4.z + eav * We4.z;
            float bw = v4.w + xr4.w + eav * We4.w;
            bx = fmaxf(bx, 0.f) + NEG_SLOPE * fminf(bx, 0.f);
            by = fmaxf(by, 0.f) + NEG_SLOPE * fminf(by, 0.f);
            bz = fmaxf(bz, 0.f) + NEG_SLOPE * fminf(bz, 0.f);
            bw = fmaxf(bw, 0.f) + NEG_SLOPE * fminf(bw, 0.f);
            float d = bx * att4.x + by * att4.y + bz * att4.z + bw * att4.w;
            d += __shfl_xor(d, 1);
            d += __shfl_xor(d, 2);
            d += __shfl_xor(d, 4);
            d += __shfl_xor(d, 8);
            float a = valid ? d : -1e30f;

            float am = fmaxf(a, __shfl_xor(a, 16));
            am = fmaxf(am, __shfl_xor(am, 32));
            const float newM = fmaxf(M, am);
            const float sc = __expf(M - newM);
            const float p = __expf(a - newM);
            float ps = p;
            ps += __shfl_xor(ps, 16);
            ps += __shfl_xor(ps, 32);
            S = S * sc + ps;
            ax = ax * sc + p * v4.x;
            ay = ay * sc + p * v4.y;
            az = az * sc + p * v4.z;
            aw = aw * sc + p * v4.w;
            M = newM;
        }

        ax += __shfl_xor(ax, 16); ax += __shfl_xor(ax, 32);
        ay += __shfl_xor(ay, 16); ay += __shfl_xor(ay, 32);
        az += __shfl_xor(az, 16); az += __shfl_xor(az, 32);
        aw += __shfl_xor(aw, 16); aw += __shfl_xor(aw, 32);

        if (g == 0) {
            const float invS = 1.0f / S;
            float4 o;
            o.x = fmaxf(ax * invS + bias4.x, 0.f);
            o.y = fmaxf(ay * invS + bias4.y, 0.f);
            o.z = fmaxf(az * invS + bias4.z, 0.f);
            o.w = fmaxf(aw * invS + bias4.w, 0.f);
            *(float4*)&H[(size_t)i * 64 + fo] = o;
        }
    }
}

// ---------------- tail: mean pool + linear + softmax ----------------

__global__ __launch_bounds__(256) void k_colsum(const float* __restrict__ H,
                                                float* __restrict__ gsum) {
    int wave = threadIdx.x >> 6, lane = threadIdx.x & 63;
    float s = 0.f;
    for (int r = blockIdx.x * 4 + wave; r < NNODES; r += gridDim.x * 4)
        s += H[(size_t)r * 64 + lane];
    __shared__ float ls[4][64];
    ls[wave][lane] = s;
    __syncthreads();
    if (wave == 0) {
        s = ls[0][lane] + ls[1][lane] + ls[2][lane] + ls[3][lane];
        atomicAdd(&gsum[lane], s);
    }
}

__global__ __launch_bounds__(64) void k_head(const float* __restrict__ gsum,
                                             const float* __restrict__ Wlin,
                                             const float* __restrict__ blin,
                                             float* __restrict__ out) {
    int lane = threadIdx.x;
    float g = gsum[lane] * (1.0f / NNODES);
    float a0 = wave_sum64(g * Wlin[lane * 2 + 0]);
    float a1 = wave_sum64(g * Wlin[lane * 2 + 1]);
    if (lane == 0) {
        float l0 = a0 + blin[0], l1 = a1 + blin[1];
        float mx = fmaxf(l0, l1);
        float e0 = __expf(l0 - mx), e1 = __expf(l1 - mx);
        float inv = 1.f / (e0 + e1);
        out[0] = e0 * inv;
        out[1] = e1 * inv;
    }
}

extern "C" void kernel_launch(void* const* d_in, const int* in_sizes, int n_in,
                              void* d_out, int out_size, void* d_ws, size_t ws_size,
                              hipStream_t stream) {
    const float* x = (const float*)d_in[0];
    const int* ei = (const int*)d_in[1];
    const float* ea = (const float*)d_in[2];
    const int* src = ei;
    const int* dst = ei + NEDGES;
    auto W = [&](int i) { return (const float*)d_in[i]; };

    char* ws = (char*)d_ws;
    size_t off = 0;
    auto alloc = [&](size_t bytes) {
        void* p = ws + off;
        off += (bytes + 255) & ~(size_t)255;
        return p;
    };
    float* XLb = (float*)alloc((size_t)NNODES * 64 * 4);
    float* XRb = (float*)alloc((size_t)NNODES * 64 * 4);
    float* Hb = (float*)alloc((size_t)NNODES * 64 * 4);
    int* rowptr = (int*)alloc((size_t)(NNODES + 1) * 4);
    int* cnt = (int*)alloc((size_t)NNODES * 4);
    int* ssorted = (int*)alloc((size_t)NEDGES * 4);
    float* easorted = (float*)alloc((size_t)NEDGES * 4);
    float* easum = (float*)alloc(4);
    float* gsum = (float*)alloc(64 * 4);
    int* bsum = (int*)alloc((size_t)SCAN_BLOCKS * 4);
    int* boff = (int*)alloc((size_t)SCAN_BLOCKS * 4);

    hipMemsetAsync(cnt, 0, (size_t)NNODES * 4, stream);
    hipMemsetAsync(easum, 0, 4, stream);
    hipMemsetAsync(gsum, 0, 64 * 4, stream);

    k_hist<<<2048, 256, 0, stream>>>(dst, ea, cnt, easum);
    k_partial<<<SCAN_BLOCKS, 256, 0, stream>>>(cnt, bsum);
    k_scanb<<<1, 512, 0, stream>>>(bsum, boff, rowptr);
    k_scanfin<<<SCAN_BLOCKS, 256, 0, stream>>>(cnt, boff, rowptr);
    hipMemsetAsync(cnt, 0, (size_t)NNODES * 4, stream);
    k_scatter<<<2048, 256, 0, stream>>>(src, dst, ea, rowptr, cnt, ssorted, easorted);

    int gemm_grid = (NNODES + 127) / 128;
    int edge_grid = (NNODES + 3) / 4;

    k_gemm<128><<<gemm_grid, 256, 0, stream>>>(x, W(3), W(4), W(5), W(6), XLb, XRb);
    k_edge<<<edge_grid, 256, 0, stream>>>(XLb, XRb, rowptr, ssorted, easorted,
                                          W(7), W(8), W(9), easum, Hb);
    k_gemm<64><<<gemm_grid, 256, 0, stream>>>(Hb, W(10), W(11), W(12), W(13), XLb, XRb);
    k_edge<<<edge_grid, 256, 0, stream>>>(XLb, XRb, rowptr, ssorted, easorted,
                                          W(14), W(15), W(16), easum, Hb);
    k_gemm<64><<<gemm_grid, 256, 0, stream>>>(Hb, W(17), W(18), W(19), W(20), XLb, XRb);
    k_edge<<<edge_grid, 256, 0, stream>>>(XLb, XRb, rowptr, ssorted, easorted,
                                          W(21), W(22), W(23), easum, Hb);

    k_colsum<<<1024, 256, 0, stream>>>(Hb, gsum);
    k_head<<<1, 64, 0, stream>>>(gsum, W(24), W(25), (float*)d_out);
}